// Round 5
// baseline (1061.321 us; speedup 1.0000x reference)
//
#include <hip/hip_runtime.h>
#include <math.h>

// Problem constants
#define NN 50000
#define GG 2500
// ws layout (float offsets)
#define WS_YG    0
#define WS_SINV  36864
#define WS_FL    (WS_SINV + 19200000)
#define WS_HEL   (WS_FL + 50000)
#define WS_LPEL  (WS_HEL + 50000)
#define WS_SCOV  (WS_LPEL + 50000)
#define WS_TOTAL (WS_SCOV + 2880000)

__device__ __forceinline__ void real_sh9(float x, float y, float z, float* o) {
  const float c0 = 0.28209479177387814f;
  const float c1 = 0.4886025119029199f;
  const float ca = 1.0925484305920792f;
  const float c20 = 0.31539156525252005f;
  const float c22 = 0.5462742152960396f;
  o[0] = c0;
  o[1] = c1 * y;
  o[2] = c1 * z;
  o[3] = c1 * x;
  o[4] = ca * x * y;
  o[5] = ca * y * z;
  o[6] = c20 * (3.f * z * z - 1.f);
  o[7] = ca * x * z;
  o[8] = c22 * (x * x - y * y);
}

// Kernel 0: Y_GRID (4096 x 9). Double-precision phase reduction to match
// numpy's float64 cos/sin of the unreduced Fibonacci angle.
__global__ void k_ygrid(float* __restrict__ yg) {
  int i = blockIdx.x * blockDim.x + threadIdx.x;
  if (i >= 4096) return;
  double fr = 0.38196601125010515 * (double)i;  // (3-sqrt5)/2 : ph/(2pi)
  fr -= floor(fr);
  float ph = (float)(fr * 6.283185307179586);
  float z = 1.0f - 2.0f * ((float)i + 0.5f) * (1.0f / 4096.0f);
  float r = sqrtf(fmaxf(1.f - z * z, 0.f));
  float x = r * cosf(ph);
  float y = r * sinf(ph);
  float sh[9];
  real_sh9(x, y, z, sh);
#pragma unroll
  for (int m = 0; m < 9; ++m) yg[i * 9 + m] = sh[m];
}

// c.{xyzw} += a.{xyzw} * s
#define FMA4(c, a, s)            \
  c.x = fmaf(a.x, s, c.x);       \
  c.y = fmaf(a.y, s, c.y);       \
  c.z = fmaf(a.z, s, c.z);       \
  c.w = fmaf(a.w, s, c.w);

// epilogue for one m-component of one slot held in ACC (float4 over 4 j's)
#define EPI_M(ACC, M, SLOTN, ISF)                                           \
  {                                                                         \
    const float e0 = ACC.x * invs, e1 = ACC.y * invs, e2 = ACC.z * invs,    \
                e3 = ACC.w * invs;                                          \
    sj0 += e0 * e0; sj1 += e1 * e1; sj2 += e2 * e2; sj3 += e3 * e3;         \
    if (ISF) {                                                              \
      float* sp_ = scov + (size_t)g * 1152 + OFF + (size_t)o4 * COMP + (M); \
      sp_[0 * COMP] = e0; sp_[1 * COMP] = e1;                               \
      sp_[2 * COMP] = e2; sp_[3 * COMP] = e3;                               \
    }                                                                       \
  }

// sinv epilogue for one slot: consumes acc set (A0..A4), writes sinv row
#define EPI_SLOT(A0, A1, A2, A3, A4, SLOTN, ISF)                            \
  {                                                                         \
    float sj0 = 1e-12f, sj1 = 1e-12f, sj2 = 1e-12f, sj3 = 1e-12f;           \
    EPI_M(A0, 0, SLOTN, ISF);                                               \
    if constexpr (COMP > 1) { EPI_M(A1, 1, SLOTN, ISF); EPI_M(A2, 2, SLOTN, ISF); } \
    if constexpr (COMP > 3) { EPI_M(A3, 3, SLOTN, ISF); EPI_M(A4, 4, SLOTN, ISF); } \
    *(float4*)(sinv + (size_t)(SLOTN) * 384 + L * 128 + o4) =               \
        make_float4(sqrtf(sj0), sqrtf(sj1), sqrtf(sj2), sqrtf(sj3));        \
  }

// Kernel 1 v6: one block per group, 320 threads = 10 slot-pairs x 32
// o-threads x 4 o. Each thread computes TWO slots (sp, sp+10), halving the
// per-group A-panel LDS re-read (v5 was LDS-return-path bound: 10 waves x
// 672 ds_read_b128 x ~12cyc = 33.6us/block of a 44.7us block). Group LDS
// instr: 6720 -> 4800. X (92 KB) + A (64 KB) staged in LDS as in v5.
template <int L, int COMP, int OFF>
__device__ __forceinline__ void cov_block(
    const float* __restrict__ X, const float* __restrict__ Wl,
    float b0, float b1, float b2, float b3,
    int n0, int floc, int g,
    float* __restrict__ sinv, float* __restrict__ scov, float* A) {
  const int t = threadIdx.x;
  __syncthreads();  // protect A across l iterations
  // A staging: 4096 float4 tasks (i in [0,128), ol4 in {0,4,...,124})
  for (int idx4 = t; idx4 < 4096; idx4 += 320) {
    const int i = idx4 >> 5, ol4 = (idx4 & 31) << 2;
    const float* wp = Wl + i * 512 + ol4;
    const float4 w0 = *(const float4*)(wp);
    const float4 w1 = *(const float4*)(wp + 128);
    const float4 w2 = *(const float4*)(wp + 256);
    const float4 w3 = *(const float4*)(wp + 384);
    float4 a;
    a.x = b0 * w0.x + b1 * w1.x + b2 * w2.x + b3 * w3.x;
    a.y = b0 * w0.y + b1 * w1.y + b2 * w2.y + b3 * w3.y;
    a.z = b0 * w0.z + b1 * w1.z + b2 * w2.z + b3 * w3.z;
    a.w = b0 * w0.w + b1 * w1.w + b2 * w2.w + b3 * w3.w;
    *(float4*)(A + i * 128 + ol4) = a;
  }
  __syncthreads();
  const int o4 = (t & 31) << 2;   // 4 contiguous o per thread (0..124)
  const int sp = t >> 5;          // slot-pair id in [0,10)
  const float* xpA = X + sp * 1152 + OFF;          // LDS row, slot sp
  const float* xpB = X + (sp + 10) * 1152 + OFF;   // LDS row, slot sp+10
  float4 aA0 = {0.f, 0.f, 0.f, 0.f}, aA1 = {0.f, 0.f, 0.f, 0.f};
  float4 aA2 = {0.f, 0.f, 0.f, 0.f}, aA3 = {0.f, 0.f, 0.f, 0.f};
  float4 aA4 = {0.f, 0.f, 0.f, 0.f};
  float4 aB0 = {0.f, 0.f, 0.f, 0.f}, aB1 = {0.f, 0.f, 0.f, 0.f};
  float4 aB2 = {0.f, 0.f, 0.f, 0.f}, aB3 = {0.f, 0.f, 0.f, 0.f};
  float4 aB4 = {0.f, 0.f, 0.f, 0.f};
  for (int i4 = 0; i4 < 128; i4 += 4) {
    const float* ap = A + i4 * 128 + o4;
    const float4 a0 = *(const float4*)(ap);
    const float4 a1 = *(const float4*)(ap + 128);
    const float4 a2 = *(const float4*)(ap + 256);
    const float4 a3 = *(const float4*)(ap + 384);
    if constexpr (COMP == 1) {
      const float4 xA = *(const float4*)(xpA + i4);
      const float4 xB = *(const float4*)(xpB + i4);
      FMA4(aA0, a0, xA.x); FMA4(aA0, a1, xA.y);
      FMA4(aA0, a2, xA.z); FMA4(aA0, a3, xA.w);
      FMA4(aB0, a0, xB.x); FMA4(aB0, a1, xB.y);
      FMA4(aB0, a2, xB.z); FMA4(aB0, a3, xB.w);
    } else if constexpr (COMP == 3) {
      const float* xqA = xpA + i4 * 3;
      const float4 xA0 = *(const float4*)(xqA);
      const float4 xA1 = *(const float4*)(xqA + 4);
      const float4 xA2 = *(const float4*)(xqA + 8);
      const float* xqB = xpB + i4 * 3;
      const float4 xB0 = *(const float4*)(xqB);
      const float4 xB1 = *(const float4*)(xqB + 4);
      const float4 xB2 = *(const float4*)(xqB + 8);
      FMA4(aA0, a0, xA0.x); FMA4(aA1, a0, xA0.y); FMA4(aA2, a0, xA0.z);
      FMA4(aA0, a1, xA0.w); FMA4(aA1, a1, xA1.x); FMA4(aA2, a1, xA1.y);
      FMA4(aA0, a2, xA1.z); FMA4(aA1, a2, xA1.w); FMA4(aA2, a2, xA2.x);
      FMA4(aA0, a3, xA2.y); FMA4(aA1, a3, xA2.z); FMA4(aA2, a3, xA2.w);
      FMA4(aB0, a0, xB0.x); FMA4(aB1, a0, xB0.y); FMA4(aB2, a0, xB0.z);
      FMA4(aB0, a1, xB0.w); FMA4(aB1, a1, xB1.x); FMA4(aB2, a1, xB1.y);
      FMA4(aB0, a2, xB1.z); FMA4(aB1, a2, xB1.w); FMA4(aB2, a2, xB2.x);
      FMA4(aB0, a3, xB2.y); FMA4(aB1, a3, xB2.z); FMA4(aB2, a3, xB2.w);
    } else {
      const float* xqA = xpA + i4 * 5;
      const float4 xA0 = *(const float4*)(xqA);
      const float4 xA1 = *(const float4*)(xqA + 4);
      const float4 xA2 = *(const float4*)(xqA + 8);
      const float4 xA3 = *(const float4*)(xqA + 12);
      const float4 xA4 = *(const float4*)(xqA + 16);
      const float* xqB = xpB + i4 * 5;
      const float4 xB0 = *(const float4*)(xqB);
      const float4 xB1 = *(const float4*)(xqB + 4);
      const float4 xB2 = *(const float4*)(xqB + 8);
      const float4 xB3 = *(const float4*)(xqB + 12);
      const float4 xB4 = *(const float4*)(xqB + 16);
      FMA4(aA0, a0, xA0.x); FMA4(aA1, a0, xA0.y); FMA4(aA2, a0, xA0.z);
      FMA4(aA3, a0, xA0.w); FMA4(aA4, a0, xA1.x);
      FMA4(aA0, a1, xA1.y); FMA4(aA1, a1, xA1.z); FMA4(aA2, a1, xA1.w);
      FMA4(aA3, a1, xA2.x); FMA4(aA4, a1, xA2.y);
      FMA4(aA0, a2, xA2.z); FMA4(aA1, a2, xA2.w); FMA4(aA2, a2, xA3.x);
      FMA4(aA3, a2, xA3.y); FMA4(aA4, a2, xA3.z);
      FMA4(aA0, a3, xA3.w); FMA4(aA1, a3, xA4.x); FMA4(aA2, a3, xA4.y);
      FMA4(aA3, a3, xA4.z); FMA4(aA4, a3, xA4.w);
      FMA4(aB0, a0, xB0.x); FMA4(aB1, a0, xB0.y); FMA4(aB2, a0, xB0.z);
      FMA4(aB3, a0, xB0.w); FMA4(aB4, a0, xB1.x);
      FMA4(aB0, a1, xB1.y); FMA4(aB1, a1, xB1.z); FMA4(aB2, a1, xB1.w);
      FMA4(aB3, a1, xB2.x); FMA4(aB4, a1, xB2.y);
      FMA4(aB0, a2, xB2.z); FMA4(aB1, a2, xB2.w); FMA4(aB2, a2, xB3.x);
      FMA4(aB3, a2, xB3.y); FMA4(aB4, a2, xB3.z);
      FMA4(aB0, a3, xB3.w); FMA4(aB1, a3, xB4.x); FMA4(aB2, a3, xB4.y);
      FMA4(aB3, a3, xB4.z); FMA4(aB4, a3, xB4.w);
    }
  }
  const float invs = 0.044194173824159216f;  // 1/sqrt(512)
  {
    const bool isfA = (sp == floc);
    EPI_SLOT(aA0, aA1, aA2, aA3, aA4, n0 + sp, isfA);
  }
  {
    const bool isfB = (sp + 10 == floc);
    EPI_SLOT(aB0, aB1, aB2, aB3, aB4, n0 + sp + 10, isfB);
  }
}

__global__ __launch_bounds__(320, 1) void k_cov(
    const float* __restrict__ s_inter, const float* __restrict__ bag,
    const int* __restrict__ ptr, const int* __restrict__ focus,
    const float* __restrict__ W_bag,
    float* __restrict__ sinv, float* __restrict__ scov) {
  __shared__ __align__(16) float A[16384];   // 64 KB: A_l[i][o] 128x128
  __shared__ __align__(16) float X[23040];   // 92 KB: 20 node rows x 1152
  const int g = blockIdx.x;
  const int t = threadIdx.x;
  const int n0 = ptr[g];
  const int nseg = ptr[g + 1] - n0;  // always 20 for this problem
  const int floc = focus[g];
  const float b0 = bag[g * 4 + 0], b1 = bag[g * 4 + 1];
  const float b2 = bag[g * 4 + 2], b3 = bag[g * 4 + 3];
  // Stage X: 5760 float4 tasks (20 rows x 288 float4), coalesced bulk loads.
  for (int idx = t; idx < 5760; idx += 320) {
    const int p = idx / 288;
    const int q4 = (idx - p * 288) << 2;
    if (p < nseg)
      *(float4*)(X + p * 1152 + q4) =
          *(const float4*)(s_inter + (size_t)(n0 + p) * 1152 + q4);
  }
  // (first barrier inside cov_block<0> makes X+A visible before compute)
  cov_block<0, 1, 0>(X, W_bag, b0, b1, b2, b3, n0, floc, g, sinv, scov, A);
  cov_block<1, 3, 128>(X, W_bag + 65536, b0, b1, b2, b3, n0, floc, g, sinv, scov, A);
  cov_block<2, 5, 512>(X, W_bag + 131072, b0, b1, b2, b3, n0, floc, g, sinv, scov, A);
}

// Kernel 2 v2: 16 nodes per 128-thread block; thread t = hidden unit t.
// s_inv staged in 64-col chunks (4 KB); after the main loop the SAME LDS
// buffer holds hidden activations at padded stride 132 (bank-conflict-free
// layer-2 dot). Total LDS ~17 KB -> ~9 blocks/CU.
__global__ __launch_bounds__(128) void k_mlp(
    const float* __restrict__ sinv, const float* __restrict__ bag,
    const int* __restrict__ batch, const int* __restrict__ element,
    const float* __restrict__ W1f, const float* __restrict__ b1f,
    const float* __restrict__ W2f, const float* __restrict__ b2f,
    const float* __restrict__ W1e, const float* __restrict__ b1e,
    const float* __restrict__ W2e, const float* __restrict__ b2e,
    float* __restrict__ flv, float* __restrict__ helv, float* __restrict__ lpelv) {
  __shared__ __align__(16) float lds[4224];  // chunk: [16][64]; later hf/he [16][132] x2
  __shared__ float els[16][4];
  const int t = threadIdx.x;
  const int n0 = blockIdx.x * 16;
  float af[16], ae[16];
#pragma unroll
  for (int p = 0; p < 16; ++p) { af[p] = 0.f; ae[p] = 0.f; }
  const float bf = b1f[t], be = b1e[t];
  for (int cb = 0; cb < 6; ++cb) {
    const int c0 = cb * 64;
    __syncthreads();
    {
      const int p = t >> 3, q = (t & 7) * 8;
      const float* src = sinv + (size_t)(n0 + p) * 384 + c0 + q;
      const float4 v0 = *(const float4*)(src);
      const float4 v1 = *(const float4*)(src + 4);
      *(float4*)(lds + p * 64 + q) = v0;
      *(float4*)(lds + p * 64 + q + 4) = v1;
    }
    __syncthreads();
    for (int cc = 0; cc < 64; cc += 4) {
      const int c = c0 + cc;
      const float wf0 = W1f[(c + 0) * 128 + t];
      const float wf1 = W1f[(c + 1) * 128 + t];
      const float wf2 = W1f[(c + 2) * 128 + t];
      const float wf3 = W1f[(c + 3) * 128 + t];
      const float we0 = W1e[(c + 0) * 128 + t];
      const float we1 = W1e[(c + 1) * 128 + t];
      const float we2 = W1e[(c + 2) * 128 + t];
      const float we3 = W1e[(c + 3) * 128 + t];
#pragma unroll
      for (int p = 0; p < 16; ++p) {
        const float4 s4 = *(const float4*)(lds + p * 64 + cc);
        af[p] = fmaf(s4.x, wf0, af[p]);
        af[p] = fmaf(s4.y, wf1, af[p]);
        af[p] = fmaf(s4.z, wf2, af[p]);
        af[p] = fmaf(s4.w, wf3, af[p]);
        ae[p] = fmaf(s4.x, we0, ae[p]);
        ae[p] = fmaf(s4.y, we1, ae[p]);
        ae[p] = fmaf(s4.z, we2, ae[p]);
        ae[p] = fmaf(s4.w, we3, ae[p]);
      }
    }
  }
  __syncthreads();
#pragma unroll
  for (int p = 0; p < 16; ++p) {
    lds[p * 132 + t] = fmaxf(af[p] + bf, 0.f);          // hf
    lds[2112 + p * 132 + t] = fmaxf(ae[p] + be, 0.f);   // he
  }
  __syncthreads();
  if (t < 80) {  // 16 nodes x (1 fl + 4 el)
    const int p = t / 5, q = t - p * 5;
    if (q == 0) {
      float s = 0.f;
      for (int j = 0; j < 128; ++j) s = fmaf(lds[p * 132 + j], W2f[j], s);
      flv[n0 + p] = s + b2f[0];
    } else {
      const int z = q - 1;
      float s = 0.f;
      for (int j = 0; j < 128; ++j) s = fmaf(lds[2112 + p * 132 + j], W2e[j * 4 + z], s);
      els[p][z] = s + b2e[z];
    }
  }
  __syncthreads();
  if (t < 16) {
    const int n = n0 + t;
    const int g = batch[n];
    const int elem = element[g];
    float v[4];
#pragma unroll
    for (int z = 0; z < 4; ++z) {
      const bool mk = bag[g * 4 + z] > 0.f;
      v[z] = mk ? els[t][z] : -1e9f;
    }
    const float mx = fmaxf(fmaxf(v[0], v[1]), fmaxf(v[2], v[3]));
    float e[4];
    float S = 0.f;
#pragma unroll
    for (int z = 0; z < 4; ++z) { e[z] = expf(v[z] - mx); S += e[z]; }
    const float iS = 1.f / S;
    float h = 0.f;
#pragma unroll
    for (int z = 0; z < 4; ++z) {
      const float pz = e[z] * iS;
      h -= pz * logf(fmaxf(pz, 1e-20f));
    }
    helv[n] = h;
    lpelv[n] = logf(e[elem] * iS + 1e-20f);
  }
}

// Kernel 3: per-group epilogue.
__global__ __launch_bounds__(128) void k_group(
    const int* __restrict__ ptr, const int* __restrict__ focus,
    const int* __restrict__ element, const float* __restrict__ distance,
    const float* __restrict__ orientation, const float* __restrict__ dls,
    const float* __restrict__ W_mix,
    const float* __restrict__ W1d, const float* __restrict__ b1d,
    const float* __restrict__ W2d, const float* __restrict__ b2d,
    const float* __restrict__ flv, const float* __restrict__ helv,
    const float* __restrict__ lpelv, const float* __restrict__ sinv,
    const float* __restrict__ scov, const float* __restrict__ yg,
    float* __restrict__ out) {
  __shared__ float fls[32];
  __shared__ float hels[32];
  __shared__ __align__(16) float svg[384];
  __shared__ float hd[128];
  __shared__ float out6[6];
  __shared__ float red[128][12];
  __shared__ float conds[9];
  __shared__ float mred[128];
  __shared__ float sred[128];
  const int g = blockIdx.x;
  const int t = threadIdx.x;
  const int n0 = ptr[g];
  const int nseg = ptr[g + 1] - n0;
  const int floc = focus[g];
  const int gi = n0 + floc;
  const int elem = element[g];
  const float dist = distance[g];
  if (t < nseg) { fls[t] = flv[n0 + t]; hels[t] = helv[n0 + t]; }
  for (int c = t; c < 384; c += 128) svg[c] = sinv[(size_t)gi * 384 + c];
  __syncthreads();
  float res_lpf = 0.f, res_ent = 0.f;
  if (t == 0) {  // focus softmax + entropies (20-long serial)
    float mx = -1e30f;
    for (int p = 0; p < nseg; ++p) mx = fmaxf(mx, fls[p]);
    float S = 0.f;
    for (int p = 0; p < nseg; ++p) S += expf(fls[p] - mx);
    const float iS = 1.f / S;
    float hfoc = 0.f, hef = 0.f;
    for (int p = 0; p < nseg; ++p) {
      const float pp = expf(fls[p] - mx) * iS;
      hfoc -= pp * logf(pp + 1e-20f);
      hef += pp * hels[p];
    }
    res_lpf = logf(expf(fls[floc] - mx) * iS + 1e-20f);
    res_ent = hfoc + hef;
  }
  // d-MLP hidden: thread t = hidden unit
  {
    float acc = b1d[t];
    for (int c = 0; c < 384; c += 4) {
      const float4 s4 = *(const float4*)(&svg[c]);
      acc = fmaf(s4.x, W1d[(c + 0) * 128 + t], acc);
      acc = fmaf(s4.y, W1d[(c + 1) * 128 + t], acc);
      acc = fmaf(s4.z, W1d[(c + 2) * 128 + t], acc);
      acc = fmaf(s4.w, W1d[(c + 3) * 128 + t], acc);
    }
    acc += W1d[(384 + elem) * 128 + t];  // one-hot element tail
    hd[t] = fmaxf(acc, 0.f);
  }
  __syncthreads();
  if (t < 6) {
    float s = 0.f;
    for (int j = 0; j < 128; ++j) s = fmaf(hd[j], W2d[j * 6 + t], s);
    out6[t] = s + b2d[t];
  }
  // Bessel mix + conditional cov partials (thread t = i index)
  {
    float bess[8];
    const float sq2d = 1.0540925533894598f;  // sqrt(2/1.8)
#pragma unroll
    for (int k = 0; k < 8; ++k)
      bess[k] = sq2d * sinf((float)(k + 1) * 3.14159265358979323846f * dist / 1.8f) / dist;
    const float invnb = 0.35355339059327373f;  // 1/sqrt(8)
    float partial[9];
    {
      float tw = 0.f;
#pragma unroll
      for (int k = 0; k < 8; ++k) tw += bess[k] * W_mix[k * 1536 + t * 4 + elem];
      tw *= invnb;
      partial[0] = scov[(size_t)g * 1152 + t] * tw;
    }
    {
      float tw = 0.f;
#pragma unroll
      for (int k = 0; k < 8; ++k) tw += bess[k] * W_mix[k * 1536 + (128 + t) * 4 + elem];
      tw *= invnb;
#pragma unroll
      for (int m = 0; m < 3; ++m) partial[1 + m] = scov[(size_t)g * 1152 + 128 + t * 3 + m] * tw;
    }
    {
      float tw = 0.f;
#pragma unroll
      for (int k = 0; k < 8; ++k) tw += bess[k] * W_mix[k * 1536 + (256 + t) * 4 + elem];
      tw *= invnb;
#pragma unroll
      for (int m = 0; m < 5; ++m) partial[4 + m] = scov[(size_t)g * 1152 + 512 + t * 5 + m] * tw;
    }
#pragma unroll
    for (int q = 0; q < 9; ++q) red[t][q] = partial[q];
  }
  __syncthreads();
  if (t < 9) {
    float s = 0.f;
    for (int i = 0; i < 128; ++i) s += red[i][t];
    conds[t] = s * 0.044194173824159216f;  // /sqrt(512)
  }
  __syncthreads();
  const float c0 = conds[0], c1 = conds[1], c2 = conds[2], c3 = conds[3];
  const float c4 = conds[4], c5 = conds[5], c6 = conds[6], c7 = conds[7];
  const float c8 = conds[8];
  // spherical logsumexp over 4096 grid points (online per thread)
  float lm = -1e30f, ls = 0.f;
  for (int p = t; p < 4096; p += 128) {
    const float* yp = yg + p * 9;
    float v = c0 * yp[0] + c1 * yp[1] + c2 * yp[2] + c3 * yp[3] + c4 * yp[4] +
              c5 * yp[5] + c6 * yp[6] + c7 * yp[7] + c8 * yp[8];
    v *= 10.0f;
    if (v > lm) { ls = ls * expf(lm - v) + 1.f; lm = v; }
    else ls += expf(v - lm);
  }
  mred[t] = lm;
  sred[t] = ls;
  __syncthreads();
  if (t == 0) {
    // distance GMM
    const float l0 = out6[0], l1 = out6[1], l2 = out6[2];
    const float lmx = fmaxf(l0, fmaxf(l1, l2));
    const float lsew = lmx + logf(expf(l0 - lmx) + expf(l1 - lmx) + expf(l2 - lmx));
    float vals[3];
#pragma unroll
    for (int k = 0; k < 3; ++k) {
      const float mean = tanhf(out6[3 + k]) * 0.45f + 1.35f;
      const float sd = fmaxf(expf(dls[k]), 1e-6f);
      const float zz = (dist - mean) / sd;
      vals[k] = (out6[k] - lsew) + (-0.5f * zz * zz - logf(sd) - 0.9189385332046727f);
    }
    const float vm = fmaxf(vals[0], fmaxf(vals[1], vals[2]));
    const float lp_dist =
        vm + logf(expf(vals[0] - vm) + expf(vals[1] - vm) + expf(vals[2] - vm));
    // merge grid lse
    float Mx = -1e30f;
    for (int i = 0; i < 128; ++i) Mx = fmaxf(Mx, mred[i]);
    float S = 0.f;
    for (int i = 0; i < 128; ++i) S += sred[i] * expf(mred[i] - Mx);
    const float logZ = Mx + logf(S) - 8.317766166719343f + 2.5310242469692907f;
    // orientation term
    float ox = orientation[g * 3 + 0], oy = orientation[g * 3 + 1], oz = orientation[g * 3 + 2];
    const float inr = 1.f / sqrtf(ox * ox + oy * oy + oz * oz);
    ox *= inr; oy *= inr; oz *= inr;
    float sh[9];
    real_sh9(ox, oy, oz, sh);
    const float fx = c0 * sh[0] + c1 * sh[1] + c2 * sh[2] + c3 * sh[3] + c4 * sh[4] +
                     c5 * sh[5] + c6 * sh[6] + c7 * sh[7] + c8 * sh[8];
    const float lp_ori = 10.0f * fx - logZ;
    out[g * 2 + 0] = res_lpf + lpelv[gi] + lp_dist + lp_ori;
    out[g * 2 + 1] = res_ent;
  }
}

extern "C" void kernel_launch(void* const* d_in, const int* in_sizes, int n_in,
                              void* d_out, int out_size, void* d_ws, size_t ws_size,
                              hipStream_t stream) {
  const float* s_inter = (const float*)d_in[0];
  const float* bag = (const float*)d_in[1];
  const int* batch = (const int*)d_in[2];
  const int* ptr = (const int*)d_in[3];
  const int* focus = (const int*)d_in[4];
  const int* element = (const int*)d_in[5];
  const float* distance = (const float*)d_in[6];
  const float* orientation = (const float*)d_in[7];
  const float* W_bag = (const float*)d_in[8];
  const float* dls = (const float*)d_in[9];
  const float* W_mix = (const float*)d_in[10];
  const float* W1f = (const float*)d_in[11];
  const float* b1f = (const float*)d_in[12];
  const float* W2f = (const float*)d_in[13];
  const float* b2f = (const float*)d_in[14];
  const float* W1e = (const float*)d_in[15];
  const float* b1e = (const float*)d_in[16];
  const float* W2e = (const float*)d_in[17];
  const float* b2e = (const float*)d_in[18];
  const float* W1d = (const float*)d_in[19];
  const float* b1d = (const float*)d_in[20];
  const float* W2d = (const float*)d_in[21];
  const float* b2d = (const float*)d_in[22];

  if (ws_size < (size_t)WS_TOTAL * sizeof(float)) return;  // need ~89 MB scratch

  float* ws = (float*)d_ws;
  float* yg = ws + WS_YG;
  float* sinv = ws + WS_SINV;
  float* flv = ws + WS_FL;
  float* helv = ws + WS_HEL;
  float* lpelv = ws + WS_LPEL;
  float* scov = ws + WS_SCOV;
  float* out = (float*)d_out;

  k_ygrid<<<dim3(32), dim3(128), 0, stream>>>(yg);
  k_cov<<<dim3(GG), dim3(320), 0, stream>>>(s_inter, bag, ptr, focus, W_bag, sinv, scov);
  k_mlp<<<dim3(NN / 16), dim3(128), 0, stream>>>(sinv, bag, batch, element,
                                                 W1f, b1f, W2f, b2f,
                                                 W1e, b1e, W2e, b2e,
                                                 flv, helv, lpelv);
  k_group<<<dim3(GG), dim3(128), 0, stream>>>(ptr, focus, element, distance, orientation,
                                              dls, W_mix, W1d, b1d, W2d, b2d,
                                              flv, helv, lpelv, sinv, scov, yg, out);
}

// Round 6
// 917.672 us; speedup vs baseline: 1.1565x; 1.1565x over previous
//
#include <hip/hip_runtime.h>
#include <math.h>

// Problem constants
#define NN 50000
#define GG 2500
// ws layout (float offsets)
#define WS_YG    0
#define WS_SINV  36864
#define WS_FL    (WS_SINV + 19200000)
#define WS_HEL   (WS_FL + 50000)
#define WS_LPEL  (WS_HEL + 50000)
#define WS_SCOV  (WS_LPEL + 50000)
#define WS_TOTAL (WS_SCOV + 2880000)

// Padded Y_GRID (4096 x 12, rows 48B -> float4-loadable) in module memory.
__device__ __align__(16) float g_yg[4096 * 12];

__device__ __forceinline__ void real_sh9(float x, float y, float z, float* o) {
  const float c0 = 0.28209479177387814f;
  const float c1 = 0.4886025119029199f;
  const float ca = 1.0925484305920792f;
  const float c20 = 0.31539156525252005f;
  const float c22 = 0.5462742152960396f;
  o[0] = c0;
  o[1] = c1 * y;
  o[2] = c1 * z;
  o[3] = c1 * x;
  o[4] = ca * x * y;
  o[5] = ca * y * z;
  o[6] = c20 * (3.f * z * z - 1.f);
  o[7] = ca * x * z;
  o[8] = c22 * (x * x - y * y);
}

// Kernel 0: Y_GRID. Double-precision phase reduction to match numpy's
// float64 cos/sin of the unreduced Fibonacci angle. Stride-12 padded rows.
__global__ void k_ygrid() {
  int i = blockIdx.x * blockDim.x + threadIdx.x;
  if (i >= 4096) return;
  double fr = 0.38196601125010515 * (double)i;  // (3-sqrt5)/2 : ph/(2pi)
  fr -= floor(fr);
  float ph = (float)(fr * 6.283185307179586);
  float z = 1.0f - 2.0f * ((float)i + 0.5f) * (1.0f / 4096.0f);
  float r = sqrtf(fmaxf(1.f - z * z, 0.f));
  float x = r * cosf(ph);
  float y = r * sinf(ph);
  float sh[9];
  real_sh9(x, y, z, sh);
#pragma unroll
  for (int m = 0; m < 9; ++m) g_yg[i * 12 + m] = sh[m];
  g_yg[i * 12 + 9] = 0.f;
  g_yg[i * 12 + 10] = 0.f;
  g_yg[i * 12 + 11] = 0.f;
}

// c.{xyzw} += a.{xyzw} * s
#define FMA4(c, a, s)            \
  c.x = fmaf(a.x, s, c.x);       \
  c.y = fmaf(a.y, s, c.y);       \
  c.z = fmaf(a.z, s, c.z);       \
  c.w = fmaf(a.w, s, c.w);

// epilogue for one m-component held in ACC (float4 over the 4 j's)
#define EPI_M(ACC, M)                                                       \
  {                                                                         \
    const float e0 = ACC.x * invs, e1 = ACC.y * invs, e2 = ACC.z * invs,    \
                e3 = ACC.w * invs;                                          \
    sj0 += e0 * e0; sj1 += e1 * e1; sj2 += e2 * e2; sj3 += e3 * e3;         \
    if (isf) {                                                              \
      float* sp = scov + (size_t)g * 1152 + OFF + (size_t)o4 * COMP + (M);  \
      sp[0 * COMP] = e0; sp[1 * COMP] = e1;                                 \
      sp[2 * COMP] = e2; sp[3 * COMP] = e3;                                 \
    }                                                                       \
  }

// Kernel 1 (v5 = best measured, 437us): one block per group, 640 threads
// (20 slots x 32 o-threads x 4 o). X panel (92 KB) + A_l (64 KB) in LDS;
// 10 waves/CU. v6 (320thr, 2 slots/thread) regressed to 570us: at 1.25
// waves/SIMD the ds_read->FMA latency is exposed — wave count IS the
// latency hiding at 1 block/CU. Do not reduce threads below 640 here.
template <int L, int COMP, int OFF>
__device__ __forceinline__ void cov_block(
    const float* __restrict__ X, const float* __restrict__ Wl,
    float b0, float b1, float b2, float b3,
    int n0, int nseg, int gi, int g,
    float* __restrict__ sinv, float* __restrict__ scov, float* A) {
  const int t = threadIdx.x;
  __syncthreads();  // protect A across l iterations
  // A staging: 4096 float4 tasks (i in [0,128), ol4 in {0,4,...,124})
  for (int idx4 = t; idx4 < 4096; idx4 += 640) {
    const int i = idx4 >> 5, ol4 = (idx4 & 31) << 2;
    const float* wp = Wl + i * 512 + ol4;
    const float4 w0 = *(const float4*)(wp);
    const float4 w1 = *(const float4*)(wp + 128);
    const float4 w2 = *(const float4*)(wp + 256);
    const float4 w3 = *(const float4*)(wp + 384);
    float4 a;
    a.x = b0 * w0.x + b1 * w1.x + b2 * w2.x + b3 * w3.x;
    a.y = b0 * w0.y + b1 * w1.y + b2 * w2.y + b3 * w3.y;
    a.z = b0 * w0.z + b1 * w1.z + b2 * w2.z + b3 * w3.z;
    a.w = b0 * w0.w + b1 * w1.w + b2 * w2.w + b3 * w3.w;
    *(float4*)(A + i * 128 + ol4) = a;
  }
  __syncthreads();
  const int o4 = (t & 31) << 2;   // 4 contiguous o per thread (0..124)
  const int slot = t >> 5;        // 20 node-slots
  if (slot < nseg) {
    const int n = n0 + slot;
    const float* xp = X + slot * 1152 + OFF;  // LDS
    float4 ac0 = {0.f, 0.f, 0.f, 0.f};
    float4 ac1 = {0.f, 0.f, 0.f, 0.f};
    float4 ac2 = {0.f, 0.f, 0.f, 0.f};
    float4 ac3 = {0.f, 0.f, 0.f, 0.f};
    float4 ac4 = {0.f, 0.f, 0.f, 0.f};
    for (int i4 = 0; i4 < 128; i4 += 4) {
      const float* ap = A + i4 * 128 + o4;
      const float4 a0 = *(const float4*)(ap);
      const float4 a1 = *(const float4*)(ap + 128);
      const float4 a2 = *(const float4*)(ap + 256);
      const float4 a3 = *(const float4*)(ap + 384);
      if constexpr (COMP == 1) {
        const float4 x0 = *(const float4*)(xp + i4);
        FMA4(ac0, a0, x0.x);
        FMA4(ac0, a1, x0.y);
        FMA4(ac0, a2, x0.z);
        FMA4(ac0, a3, x0.w);
      } else if constexpr (COMP == 3) {
        const float* xq = xp + i4 * 3;
        const float4 x0 = *(const float4*)(xq);
        const float4 x1 = *(const float4*)(xq + 4);
        const float4 x2 = *(const float4*)(xq + 8);
        FMA4(ac0, a0, x0.x); FMA4(ac1, a0, x0.y); FMA4(ac2, a0, x0.z);
        FMA4(ac0, a1, x0.w); FMA4(ac1, a1, x1.x); FMA4(ac2, a1, x1.y);
        FMA4(ac0, a2, x1.z); FMA4(ac1, a2, x1.w); FMA4(ac2, a2, x2.x);
        FMA4(ac0, a3, x2.y); FMA4(ac1, a3, x2.z); FMA4(ac2, a3, x2.w);
      } else {
        const float* xq = xp + i4 * 5;
        const float4 x0 = *(const float4*)(xq);
        const float4 x1 = *(const float4*)(xq + 4);
        const float4 x2 = *(const float4*)(xq + 8);
        const float4 x3 = *(const float4*)(xq + 12);
        const float4 x4 = *(const float4*)(xq + 16);
        FMA4(ac0, a0, x0.x); FMA4(ac1, a0, x0.y); FMA4(ac2, a0, x0.z);
        FMA4(ac3, a0, x0.w); FMA4(ac4, a0, x1.x);
        FMA4(ac0, a1, x1.y); FMA4(ac1, a1, x1.z); FMA4(ac2, a1, x1.w);
        FMA4(ac3, a1, x2.x); FMA4(ac4, a1, x2.y);
        FMA4(ac0, a2, x2.z); FMA4(ac1, a2, x2.w); FMA4(ac2, a2, x3.x);
        FMA4(ac3, a2, x3.y); FMA4(ac4, a2, x3.z);
        FMA4(ac0, a3, x3.w); FMA4(ac1, a3, x4.x); FMA4(ac2, a3, x4.y);
        FMA4(ac3, a3, x4.z); FMA4(ac4, a3, x4.w);
      }
    }
    const bool isf = (n == gi);
    const float invs = 0.044194173824159216f;  // 1/sqrt(512)
    float sj0 = 1e-12f, sj1 = 1e-12f, sj2 = 1e-12f, sj3 = 1e-12f;
    EPI_M(ac0, 0);
    if constexpr (COMP > 1) {
      EPI_M(ac1, 1);
      EPI_M(ac2, 2);
    }
    if constexpr (COMP > 3) {
      EPI_M(ac3, 3);
      EPI_M(ac4, 4);
    }
    *(float4*)(sinv + (size_t)n * 384 + L * 128 + o4) =
        make_float4(sqrtf(sj0), sqrtf(sj1), sqrtf(sj2), sqrtf(sj3));
  }
}

__global__ __launch_bounds__(640) void k_cov(
    const float* __restrict__ s_inter, const float* __restrict__ bag,
    const int* __restrict__ ptr, const int* __restrict__ focus,
    const float* __restrict__ W_bag,
    float* __restrict__ sinv, float* __restrict__ scov) {
  __shared__ __align__(16) float A[16384];   // 64 KB: A_l[i][o] 128x128
  __shared__ __align__(16) float X[23040];   // 92 KB: 20 node rows x 1152
  const int g = blockIdx.x;
  const int t = threadIdx.x;
  const int n0 = ptr[g];
  const int nseg = ptr[g + 1] - n0;
  const int gi = n0 + focus[g];
  const float b0 = bag[g * 4 + 0], b1 = bag[g * 4 + 1];
  const float b2 = bag[g * 4 + 2], b3 = bag[g * 4 + 3];
  // Stage X: 5760 float4 tasks (20 rows x 288 float4), coalesced bulk loads.
  for (int idx = t; idx < 5760; idx += 640) {
    const int p = idx / 288;
    const int q4 = (idx - p * 288) << 2;
    if (p < nseg)
      *(float4*)(X + p * 1152 + q4) =
          *(const float4*)(s_inter + (size_t)(n0 + p) * 1152 + q4);
  }
  // (first barrier inside cov_block<0> makes X+A visible before compute)
  cov_block<0, 1, 0>(X, W_bag, b0, b1, b2, b3, n0, nseg, gi, g, sinv, scov, A);
  cov_block<1, 3, 128>(X, W_bag + 65536, b0, b1, b2, b3, n0, nseg, gi, g, sinv, scov, A);
  cov_block<2, 5, 512>(X, W_bag + 131072, b0, b1, b2, b3, n0, nseg, gi, g, sinv, scov, A);
}

// Kernel 2 v3: 32 nodes per 128-thread block (was 16). W1f/W1e (384 KB) is
// re-loaded per block, so doubling nodes/block halves per-node W-load
// overhead (768 scalar loads/thread amortized over 2x FMAs). Layer-2 runs
// as two sequential LDS passes (hf then he in the same [32][132] buffer)
// to keep LDS at ~17 KB. All acc arrays statically indexed (rule #20).
__global__ __launch_bounds__(128) void k_mlp(
    const float* __restrict__ sinv, const float* __restrict__ bag,
    const int* __restrict__ batch, const int* __restrict__ element,
    const float* __restrict__ W1f, const float* __restrict__ b1f,
    const float* __restrict__ W2f, const float* __restrict__ b2f,
    const float* __restrict__ W1e, const float* __restrict__ b1e,
    const float* __restrict__ W2e, const float* __restrict__ b2e,
    float* __restrict__ flv, float* __restrict__ helv, float* __restrict__ lpelv) {
  __shared__ __align__(16) float lds[4224];  // chunk [32][64]=2048; passes use [32][132]=4224
  __shared__ float els[32][4];
  const int t = threadIdx.x;
  const int n0 = blockIdx.x * 32;
  float af[32], ae[32];
#pragma unroll
  for (int p = 0; p < 32; ++p) { af[p] = 0.f; ae[p] = 0.f; }
  const float bf = b1f[t], be = b1e[t];
  for (int cb = 0; cb < 6; ++cb) {
    const int c0 = cb * 64;
    __syncthreads();
#pragma unroll
    for (int k = 0; k < 4; ++k) {  // stage [32][64] chunk: 512 float4 tasks
      const int idx = t + k * 128;
      const int p = idx >> 4, q = (idx & 15) * 4;
      float4 v = make_float4(0.f, 0.f, 0.f, 0.f);
      if (n0 + p < NN)
        v = *(const float4*)(sinv + (size_t)(n0 + p) * 384 + c0 + q);
      *(float4*)(lds + p * 64 + q) = v;
    }
    __syncthreads();
    for (int cc = 0; cc < 64; cc += 4) {
      const int c = c0 + cc;
      const float wf0 = W1f[(c + 0) * 128 + t];
      const float wf1 = W1f[(c + 1) * 128 + t];
      const float wf2 = W1f[(c + 2) * 128 + t];
      const float wf3 = W1f[(c + 3) * 128 + t];
      const float we0 = W1e[(c + 0) * 128 + t];
      const float we1 = W1e[(c + 1) * 128 + t];
      const float we2 = W1e[(c + 2) * 128 + t];
      const float we3 = W1e[(c + 3) * 128 + t];
#pragma unroll
      for (int p = 0; p < 32; ++p) {
        const float4 s4 = *(const float4*)(lds + p * 64 + cc);
        af[p] = fmaf(s4.x, wf0, af[p]);
        af[p] = fmaf(s4.y, wf1, af[p]);
        af[p] = fmaf(s4.z, wf2, af[p]);
        af[p] = fmaf(s4.w, wf3, af[p]);
        ae[p] = fmaf(s4.x, we0, ae[p]);
        ae[p] = fmaf(s4.y, we1, ae[p]);
        ae[p] = fmaf(s4.z, we2, ae[p]);
        ae[p] = fmaf(s4.w, we3, ae[p]);
      }
    }
  }
  // layer 2, pass 1: focus logit
  __syncthreads();
#pragma unroll
  for (int p = 0; p < 32; ++p) lds[p * 132 + t] = fmaxf(af[p] + bf, 0.f);
  __syncthreads();
  if (t < 32) {
    float s = 0.f;
    for (int j = 0; j < 128; ++j) s = fmaf(lds[t * 132 + j], W2f[j], s);
    if (n0 + t < NN) flv[n0 + t] = s + b2f[0];
  }
  __syncthreads();
  // layer 2, pass 2: element logits
#pragma unroll
  for (int p = 0; p < 32; ++p) lds[p * 132 + t] = fmaxf(ae[p] + be, 0.f);
  __syncthreads();
  {
    const int p = t >> 2, z = t & 3;  // 32 nodes x 4 el, all 128 threads
    float s = 0.f;
    for (int j = 0; j < 128; ++j) s = fmaf(lds[p * 132 + j], W2e[j * 4 + z], s);
    els[p][z] = s + b2e[z];
  }
  __syncthreads();
  if (t < 32) {
    const int n = n0 + t;
    if (n < NN) {
      const int g = batch[n];
      const int elem = element[g];
      float v[4];
#pragma unroll
      for (int z = 0; z < 4; ++z) {
        const bool mk = bag[g * 4 + z] > 0.f;
        v[z] = mk ? els[t][z] : -1e9f;
      }
      const float mx = fmaxf(fmaxf(v[0], v[1]), fmaxf(v[2], v[3]));
      float e[4];
      float S = 0.f;
#pragma unroll
      for (int z = 0; z < 4; ++z) { e[z] = expf(v[z] - mx); S += e[z]; }
      const float iS = 1.f / S;
      float h = 0.f;
#pragma unroll
      for (int z = 0; z < 4; ++z) {
        const float pz = e[z] * iS;
        h -= pz * logf(fmaxf(pz, 1e-20f));
      }
      helv[n] = h;
      lpelv[n] = logf(e[elem] * iS + 1e-20f);
    }
  }
}

// Kernel 3: per-group epilogue. LSE grid loop now float4 over padded g_yg.
__global__ __launch_bounds__(128) void k_group(
    const int* __restrict__ ptr, const int* __restrict__ focus,
    const int* __restrict__ element, const float* __restrict__ distance,
    const float* __restrict__ orientation, const float* __restrict__ dls,
    const float* __restrict__ W_mix,
    const float* __restrict__ W1d, const float* __restrict__ b1d,
    const float* __restrict__ W2d, const float* __restrict__ b2d,
    const float* __restrict__ flv, const float* __restrict__ helv,
    const float* __restrict__ lpelv, const float* __restrict__ sinv,
    const float* __restrict__ scov,
    float* __restrict__ out) {
  __shared__ float fls[32];
  __shared__ float hels[32];
  __shared__ __align__(16) float svg[384];
  __shared__ float hd[128];
  __shared__ float out6[6];
  __shared__ float red[128][12];
  __shared__ float conds[9];
  __shared__ float mred[128];
  __shared__ float sred[128];
  const int g = blockIdx.x;
  const int t = threadIdx.x;
  const int n0 = ptr[g];
  const int nseg = ptr[g + 1] - n0;
  const int floc = focus[g];
  const int gi = n0 + floc;
  const int elem = element[g];
  const float dist = distance[g];
  if (t < nseg) { fls[t] = flv[n0 + t]; hels[t] = helv[n0 + t]; }
  for (int c = t; c < 384; c += 128) svg[c] = sinv[(size_t)gi * 384 + c];
  __syncthreads();
  float res_lpf = 0.f, res_ent = 0.f;
  if (t == 0) {  // focus softmax + entropies (20-long serial)
    float mx = -1e30f;
    for (int p = 0; p < nseg; ++p) mx = fmaxf(mx, fls[p]);
    float S = 0.f;
    for (int p = 0; p < nseg; ++p) S += expf(fls[p] - mx);
    const float iS = 1.f / S;
    float hfoc = 0.f, hef = 0.f;
    for (int p = 0; p < nseg; ++p) {
      const float pp = expf(fls[p] - mx) * iS;
      hfoc -= pp * logf(pp + 1e-20f);
      hef += pp * hels[p];
    }
    res_lpf = logf(expf(fls[floc] - mx) * iS + 1e-20f);
    res_ent = hfoc + hef;
  }
  // d-MLP hidden: thread t = hidden unit
  {
    float acc = b1d[t];
    for (int c = 0; c < 384; c += 4) {
      const float4 s4 = *(const float4*)(&svg[c]);
      acc = fmaf(s4.x, W1d[(c + 0) * 128 + t], acc);
      acc = fmaf(s4.y, W1d[(c + 1) * 128 + t], acc);
      acc = fmaf(s4.z, W1d[(c + 2) * 128 + t], acc);
      acc = fmaf(s4.w, W1d[(c + 3) * 128 + t], acc);
    }
    acc += W1d[(384 + elem) * 128 + t];  // one-hot element tail
    hd[t] = fmaxf(acc, 0.f);
  }
  __syncthreads();
  if (t < 6) {
    float s = 0.f;
    for (int j = 0; j < 128; ++j) s = fmaf(hd[j], W2d[j * 6 + t], s);
    out6[t] = s + b2d[t];
  }
  // Bessel mix + conditional cov partials (thread t = i index)
  {
    float bess[8];
    const float sq2d = 1.0540925533894598f;  // sqrt(2/1.8)
#pragma unroll
    for (int k = 0; k < 8; ++k)
      bess[k] = sq2d * sinf((float)(k + 1) * 3.14159265358979323846f * dist / 1.8f) / dist;
    const float invnb = 0.35355339059327373f;  // 1/sqrt(8)
    float partial[9];
    {
      float tw = 0.f;
#pragma unroll
      for (int k = 0; k < 8; ++k) tw += bess[k] * W_mix[k * 1536 + t * 4 + elem];
      tw *= invnb;
      partial[0] = scov[(size_t)g * 1152 + t] * tw;
    }
    {
      float tw = 0.f;
#pragma unroll
      for (int k = 0; k < 8; ++k) tw += bess[k] * W_mix[k * 1536 + (128 + t) * 4 + elem];
      tw *= invnb;
#pragma unroll
      for (int m = 0; m < 3; ++m) partial[1 + m] = scov[(size_t)g * 1152 + 128 + t * 3 + m] * tw;
    }
    {
      float tw = 0.f;
#pragma unroll
      for (int k = 0; k < 8; ++k) tw += bess[k] * W_mix[k * 1536 + (256 + t) * 4 + elem];
      tw *= invnb;
#pragma unroll
      for (int m = 0; m < 5; ++m) partial[4 + m] = scov[(size_t)g * 1152 + 512 + t * 5 + m] * tw;
    }
#pragma unroll
    for (int q = 0; q < 9; ++q) red[t][q] = partial[q];
  }
  __syncthreads();
  if (t < 9) {
    float s = 0.f;
    for (int i = 0; i < 128; ++i) s += red[i][t];
    conds[t] = s * 0.044194173824159216f;  // /sqrt(512)
  }
  __syncthreads();
  const float c0 = conds[0], c1 = conds[1], c2 = conds[2], c3 = conds[3];
  const float c4 = conds[4], c5 = conds[5], c6 = conds[6], c7 = conds[7];
  const float c8 = conds[8];
  // spherical logsumexp over 4096 grid points (online per thread)
  float lm = -1e30f, ls = 0.f;
  for (int p = t; p < 4096; p += 128) {
    const float* yp = g_yg + p * 12;
    const float4 y0 = *(const float4*)(yp);
    const float4 y1 = *(const float4*)(yp + 4);
    const float4 y2 = *(const float4*)(yp + 8);
    float v = c0 * y0.x + c1 * y0.y + c2 * y0.z + c3 * y0.w + c4 * y1.x +
              c5 * y1.y + c6 * y1.z + c7 * y1.w + c8 * y2.x;
    v *= 10.0f;
    if (v > lm) { ls = ls * expf(lm - v) + 1.f; lm = v; }
    else ls += expf(v - lm);
  }
  mred[t] = lm;
  sred[t] = ls;
  __syncthreads();
  if (t == 0) {
    // distance GMM
    const float l0 = out6[0], l1 = out6[1], l2 = out6[2];
    const float lmx = fmaxf(l0, fmaxf(l1, l2));
    const float lsew = lmx + logf(expf(l0 - lmx) + expf(l1 - lmx) + expf(l2 - lmx));
    float vals[3];
#pragma unroll
    for (int k = 0; k < 3; ++k) {
      const float mean = tanhf(out6[3 + k]) * 0.45f + 1.35f;
      const float sd = fmaxf(expf(dls[k]), 1e-6f);
      const float zz = (dist - mean) / sd;
      vals[k] = (out6[k] - lsew) + (-0.5f * zz * zz - logf(sd) - 0.9189385332046727f);
    }
    const float vm = fmaxf(vals[0], fmaxf(vals[1], vals[2]));
    const float lp_dist =
        vm + logf(expf(vals[0] - vm) + expf(vals[1] - vm) + expf(vals[2] - vm));
    // merge grid lse
    float Mx = -1e30f;
    for (int i = 0; i < 128; ++i) Mx = fmaxf(Mx, mred[i]);
    float S = 0.f;
    for (int i = 0; i < 128; ++i) S += sred[i] * expf(mred[i] - Mx);
    const float logZ = Mx + logf(S) - 8.317766166719343f + 2.5310242469692907f;
    // orientation term
    float ox = orientation[g * 3 + 0], oy = orientation[g * 3 + 1], oz = orientation[g * 3 + 2];
    const float inr = 1.f / sqrtf(ox * ox + oy * oy + oz * oz);
    ox *= inr; oy *= inr; oz *= inr;
    float sh[9];
    real_sh9(ox, oy, oz, sh);
    const float fx = c0 * sh[0] + c1 * sh[1] + c2 * sh[2] + c3 * sh[3] + c4 * sh[4] +
                     c5 * sh[5] + c6 * sh[6] + c7 * sh[7] + c8 * sh[8];
    const float lp_ori = 10.0f * fx - logZ;
    out[g * 2 + 0] = res_lpf + lpelv[gi] + lp_dist + lp_ori;
    out[g * 2 + 1] = res_ent;
  }
}

extern "C" void kernel_launch(void* const* d_in, const int* in_sizes, int n_in,
                              void* d_out, int out_size, void* d_ws, size_t ws_size,
                              hipStream_t stream) {
  const float* s_inter = (const float*)d_in[0];
  const float* bag = (const float*)d_in[1];
  const int* batch = (const int*)d_in[2];
  const int* ptr = (const int*)d_in[3];
  const int* focus = (const int*)d_in[4];
  const int* element = (const int*)d_in[5];
  const float* distance = (const float*)d_in[6];
  const float* orientation = (const float*)d_in[7];
  const float* W_bag = (const float*)d_in[8];
  const float* dls = (const float*)d_in[9];
  const float* W_mix = (const float*)d_in[10];
  const float* W1f = (const float*)d_in[11];
  const float* b1f = (const float*)d_in[12];
  const float* W2f = (const float*)d_in[13];
  const float* b2f = (const float*)d_in[14];
  const float* W1e = (const float*)d_in[15];
  const float* b1e = (const float*)d_in[16];
  const float* W2e = (const float*)d_in[17];
  const float* b2e = (const float*)d_in[18];
  const float* W1d = (const float*)d_in[19];
  const float* b1d = (const float*)d_in[20];
  const float* W2d = (const float*)d_in[21];
  const float* b2d = (const float*)d_in[22];

  if (ws_size < (size_t)WS_TOTAL * sizeof(float)) return;  // need ~89 MB scratch

  float* ws = (float*)d_ws;
  float* sinv = ws + WS_SINV;
  float* flv = ws + WS_FL;
  float* helv = ws + WS_HEL;
  float* lpelv = ws + WS_LPEL;
  float* scov = ws + WS_SCOV;
  float* out = (float*)d_out;

  k_ygrid<<<dim3(32), dim3(128), 0, stream>>>();
  k_cov<<<dim3(GG), dim3(640), 0, stream>>>(s_inter, bag, ptr, focus, W_bag, sinv, scov);
  k_mlp<<<dim3((NN + 31) / 32), dim3(128), 0, stream>>>(sinv, bag, batch, element,
                                                        W1f, b1f, W2f, b2f,
                                                        W1e, b1e, W2e, b2e,
                                                        flv, helv, lpelv);
  k_group<<<dim3(GG), dim3(128), 0, stream>>>(ptr, focus, element, distance, orientation,
                                              dls, W_mix, W1d, b1d, W2d, b2d,
                                              flv, helv, lpelv, sinv, scov, out);
}